// Round 8
// baseline (87.222 us; speedup 1.0000x reference)
//
#include <hip/hip_runtime.h>

// DNM dendritic layer: out[b,o] = max(0, 0.25*S - 0.05),
//   S = sum_{m,i} relu(fma(x[b,i], W[o,m,i], -q[o,m,i]))
// B=512, OUT=128, M=8, IN=512.
//
// R1-R7 findings: VALU-issue is down to ~6us (fp16 pk + dot2), but an
// invariant ~28us "non-issue" wall survives every stage/barrier variant;
// measured occupancy ~17% => CUs mostly ramping/draining short-lived blocks.
// R8: x-stationary waves. In fp16 a wave's 8 b-rows fit in 32 VGPRs
// (8 x h8 per lane). Load x once, then stream 32 (o,m) W/q rows from
// global/L2 with a 2-deep prefetch; W/q shared across the 8 in-register
// b's (no LDS, no __syncthreads, waves fully independent, ~2.5us of
// uninterrupted compute each). 2048 waves = 8/CU.
// Kept lessons: no VGPR cap (R2), no over-unroll of the streaming loop
// (R3), fp16 terms + fp32 dot2 accumulate (R7, absmax 0.5 vs thr 2.32).

#define OUTN 128
#define MM   8
#define INN  512

typedef float    f4 __attribute__((ext_vector_type(4)));
typedef _Float16 h2 __attribute__((ext_vector_type(2)));
typedef _Float16 h4 __attribute__((ext_vector_type(4)));
typedef _Float16 h8 __attribute__((ext_vector_type(8)));

// ws layout (halfs): xh [0, 262144) | Wh | qh. 2.62 MB of d_ws.
#define XH_ELEMS 262144   // 512*512
#define WH_ELEMS 524288   // 128*8*512

// Convert x,W,q -> fp16. 327680 f4-groups = 1280 blocks * 256 threads.
__global__ __launch_bounds__(256) void cvt_kernel(
    const float* __restrict__ x, const float* __restrict__ W,
    const float* __restrict__ q, _Float16* __restrict__ h)
{
    const int j = blockIdx.x * 256 + threadIdx.x;   // f4 index
    f4 v;
    if (j < 65536)        v = ((const f4*)x)[j];
    else if (j < 196608)  v = ((const f4*)W)[j - 65536];
    else                  v = ((const f4*)q)[j - 196608];
    ((h4*)h)[j] = __builtin_convertvector(v, h4);   // RNE
}

// 512 blocks * 4 waves = 2048 independent waves (no barrier, no LDS).
// Wave id = 64 b-groups (8 b each) x 32 o-groups (4 o each).
// Per wave: x (8 b-rows) resident in 32 VGPRs; stream 4o*8m W/q rows.
__global__ __launch_bounds__(256) void dnm_kernel(
    const _Float16* __restrict__ xh,   // [B, IN]
    const _Float16* __restrict__ Wh,   // [OUT, M, IN]
    const _Float16* __restrict__ qh,   // [OUT, M, IN]
    float* __restrict__ out)           // [B, OUT]
{
    const int tid  = threadIdx.x;
    const int wave = tid >> 6;
    const int lane = tid & 63;
    const int flat = blockIdx.x * 4 + wave;   // [0, 2048)
    const int ogrp = flat & 31;               // 32 groups of 4 o
    const int bgrp = flat >> 5;               // 64 groups of 8 b
    const int o0   = ogrp * 4;
    const int b0   = bgrp * 8;
    const int i0   = lane * 8;                // this lane's 8 i's (16B)

    // x-stationary: 8 rows x h8 = 32 VGPRs, loaded once per wave.
    h8 xv[8];
    #pragma unroll
    for (int b = 0; b < 8; ++b)
        xv[b] = *(const h8*)(xh + (size_t)(b0 + b) * INN + i0);

    float acc[32];   // [o_local*8 + b]
    #pragma unroll
    for (int j = 0; j < 32; ++j) acc[j] = 0.0f;

    const h2 one = {(_Float16)1.0f, (_Float16)1.0f};
    const size_t row0 = ((size_t)o0 * MM) * INN + i0;

    // Stream 32 (o,m) rows with a 2-deep prefetch; unroll 1 keeps exactly
    // one prefetch depth live (R3 spill lesson).
    h8 wc = *(const h8*)(Wh + row0);
    h8 qc = *(const h8*)(qh + row0);
    #pragma unroll 1
    for (int om = 0; om < 32; ++om) {
        h8 wn, qn;
        if (om < 31) {
            const size_t rn = row0 + (size_t)(om + 1) * INN;
            wn = *(const h8*)(Wh + rn);
            qn = *(const h8*)(qh + rn);
        }
        float* ao = acc + (om >> 3) * 8;      // o_local = om>>3, m = om&7
        #pragma unroll
        for (int b = 0; b < 8; ++b) {
            #pragma unroll
            for (int p = 0; p < 4; ++p) {
                h2 xx = {xv[b][2 * p], xv[b][2 * p + 1]};
                h2 ww = {wc[2 * p], wc[2 * p + 1]};
                h2 qq = {qc[2 * p], qc[2 * p + 1]};
                // v_pk_fma_f16 + v_pk_max_f16 + v_dot2_f32_f16
                h2 t = __builtin_elementwise_fma(xx, ww, -qq);
                t = __builtin_elementwise_max(t, (h2)(_Float16)0.0f);
#if __has_builtin(__builtin_amdgcn_fdot2)
                ao[b] = __builtin_amdgcn_fdot2(t, one, ao[b], false);
#else
                ao[b] += (float)t[0] + (float)t[1];
#endif
            }
        }
        wc = wn; qc = qn;
    }

    // Butterfly-reduce all 32 accs across 64 lanes (sum over i).
    #pragma unroll
    for (int j = 0; j < 32; ++j) {
        float v = acc[j];
        v += __shfl_xor(v, 1, 64);
        v += __shfl_xor(v, 2, 64);
        v += __shfl_xor(v, 4, 64);
        v += __shfl_xor(v, 8, 64);
        v += __shfl_xor(v, 16, 64);
        v += __shfl_xor(v, 32, 64);
        acc[j] = v;   // now uniform across the wave
    }

    // Lane b (0..7) writes out[b0+b, o0..o0+3] as one f4 (o0 is 4-aligned).
    if (lane < 8) {
        const int b = lane;
        f4 r;
        #pragma unroll
        for (int ol = 0; ol < 4; ++ol) {
            float v = 0.25f * acc[ol * 8 + b] - 0.05f;   // K*K*S - K*QS
            r[ol] = fmaxf(v, 0.0f);
        }
        *(f4*)(out + (size_t)(b0 + b) * OUTN + o0) = r;
    }
}

extern "C" void kernel_launch(void* const* d_in, const int* in_sizes, int n_in,
                              void* d_out, int out_size, void* d_ws, size_t ws_size,
                              hipStream_t stream) {
    const float* x = (const float*)d_in[0];
    const float* W = (const float*)d_in[1];
    const float* q = (const float*)d_in[2];
    float* out = (float*)d_out;
    _Float16* h = (_Float16*)d_ws;

    cvt_kernel<<<dim3(1280), dim3(256), 0, stream>>>(x, W, q, h);

    const _Float16* xh = h;
    const _Float16* Wh = h + XH_ELEMS;
    const _Float16* qh = h + XH_ELEMS + WH_ELEMS;
    dnm_kernel<<<dim3(512), dim3(256), 0, stream>>>(xh, Wh, qh, out);
}

// Round 9
// 84.245 us; speedup vs baseline: 1.0353x; 1.0353x over previous
//
#include <hip/hip_runtime.h>

// DNM dendritic layer: out[b,o] = max(0, 0.25*S - 0.05),
//   S = sum_{m,i} relu(fma(x[b,i], W[o,m,i], -q[o,m,i]))
// B=512, OUT=128, M=8, IN=512.
//
// R9: long-lived waves. Grid 512 = 128 o x 4 bgroups, 4 waves/block.
// Stage W[o],q[o] (16KB fp16) ONCE per block; each wave register-caches all
// 16 fragments (64 VGPRs) from LDS, then 4 passes x 8 b with x double-
// buffered across passes. Steady-state m-loop = 768 straight-line pk-f16
// insts, zero memory ops. Per-CU VALU issue = 5.1us; everything else
// (staging, x loads, epilogues) amortized or overlapped.
// Kept: fp16 terms + fp32 dot2 (R7, absmax 0.5 vs thr 2.32), no VGPR cap
// (R2), unroll 1 on the pass loop (R3), LDS staging (R4 > no-LDS R6/R8).

#define OUTN 128
#define MM   8
#define INN  512

typedef float    f4 __attribute__((ext_vector_type(4)));
typedef _Float16 h2 __attribute__((ext_vector_type(2)));
typedef _Float16 h4 __attribute__((ext_vector_type(4)));
typedef _Float16 h8 __attribute__((ext_vector_type(8)));

// ws layout (halfs): xh [0, 262144) | Wh | qh. 2.62 MB of d_ws.
#define XH_ELEMS 262144   // 512*512
#define WH_ELEMS 524288   // 128*8*512

// Convert x,W,q -> fp16. 327680 f4-groups = 1280 blocks * 256 threads.
__global__ __launch_bounds__(256) void cvt_kernel(
    const float* __restrict__ x, const float* __restrict__ W,
    const float* __restrict__ q, _Float16* __restrict__ h)
{
    const int j = blockIdx.x * 256 + threadIdx.x;   // f4 index
    f4 v;
    if (j < 65536)        v = ((const f4*)x)[j];
    else if (j < 196608)  v = ((const f4*)W)[j - 65536];
    else                  v = ((const f4*)q)[j - 196608];
    ((h4*)h)[j] = __builtin_convertvector(v, h4);   // RNE
}

// Block: 256 threads = 4 waves, one o, 128 b's (32 per wave, 4 passes of 8).
// Grid: 128 o * 4 b-groups = 512 blocks. LDS 16 KB.
__global__ __launch_bounds__(256) void dnm_kernel(
    const _Float16* __restrict__ xh,   // [B, IN]
    const _Float16* __restrict__ Wh,   // [OUT, M, IN]
    const _Float16* __restrict__ qh,   // [OUT, M, IN]
    float* __restrict__ out)           // [B, OUT]
{
    __shared__ _Float16 lds_w[MM * INN];   // 8 KB
    __shared__ _Float16 lds_q[MM * INN];   // 8 KB

    const int tid  = threadIdx.x;
    const int o    = blockIdx.x >> 2;
    const int bgrp = blockIdx.x & 3;
    const int wave = tid >> 6;
    const int lane = tid & 63;
    const int i0   = lane * 8;                 // this lane's 8 i's (16B)
    const int bw   = bgrp * 128 + wave * 32;   // wave's 32 b's

    // Stage W[o], q[o] into LDS (coalesced f4; 2 chunks each per thread).
    {
        const f4* Wg = (const f4*)(Wh + (size_t)o * MM * INN);
        const f4* qg = (const f4*)(qh + (size_t)o * MM * INN);
        f4* lw = (f4*)lds_w;
        f4* lq = (f4*)lds_q;
        lw[tid]       = Wg[tid];
        lw[tid + 256] = Wg[tid + 256];
        lq[tid]       = qg[tid];
        lq[tid + 256] = qg[tid + 256];
    }

    // Prefetch pass-0 x before the barrier (overlaps staging).
    h8 xv[8], xn[8];
    #pragma unroll
    for (int b = 0; b < 8; ++b)
        xv[b] = *(const h8*)(xh + (size_t)(bw + b) * INN + i0);

    __syncthreads();

    // Register-cache ALL fragments once: 16 ds_read_b128, 64 VGPRs.
    // Steady-state m-loop then has zero memory operations.
    h8 wf[MM], qf[MM];
    #pragma unroll
    for (int m = 0; m < MM; ++m) {
        wf[m] = *(const h8*)(lds_w + m * INN + i0);
        qf[m] = *(const h8*)(lds_q + m * INN + i0);
    }

    const h2 one = {(_Float16)1.0f, (_Float16)1.0f};

    // 4 passes of 8 b's; x double-buffered across passes (R5's prefetch is
    // sound here because compute-per-prefetch is 4x larger). unroll 1 keeps
    // one prefetch depth live (R3 spill lesson).
    #pragma unroll 1
    for (int pass = 0; pass < 4; ++pass) {
        if (pass < 3) {
            #pragma unroll
            for (int b = 0; b < 8; ++b)
                xn[b] = *(const h8*)(xh + (size_t)(bw + (pass + 1) * 8 + b) * INN + i0);
        }

        float acc[8];
        #pragma unroll
        for (int b = 0; b < 8; ++b) acc[b] = 0.0f;

        // 768 straight-line VALU insts: pk_fma + pk_max + dot2 per h2.
        #pragma unroll
        for (int m = 0; m < MM; ++m) {
            #pragma unroll
            for (int b = 0; b < 8; ++b) {
                #pragma unroll
                for (int p = 0; p < 4; ++p) {
                    h2 xx = {xv[b][2 * p], xv[b][2 * p + 1]};
                    h2 ww = {wf[m][2 * p], wf[m][2 * p + 1]};
                    h2 qq = {qf[m][2 * p], qf[m][2 * p + 1]};
                    h2 t = __builtin_elementwise_fma(xx, ww, -qq);
                    t = __builtin_elementwise_max(t, (h2)(_Float16)0.0f);
#if __has_builtin(__builtin_amdgcn_fdot2)
                    acc[b] = __builtin_amdgcn_fdot2(t, one, acc[b], false);
#else
                    acc[b] += (float)t[0] + (float)t[1];
#endif
                }
            }
        }

        // Reduce each acc over the 64 lanes; lane b writes (bw+pass*8+b, o).
        const int b0 = bw + pass * 8;
        #pragma unroll
        for (int b = 0; b < 8; ++b) {
            float v = acc[b];
            v += __shfl_xor(v, 1, 64);
            v += __shfl_xor(v, 2, 64);
            v += __shfl_xor(v, 4, 64);
            v += __shfl_xor(v, 8, 64);
            v += __shfl_xor(v, 16, 64);
            v += __shfl_xor(v, 32, 64);
            if (lane == b) {
                float r = 0.25f * v - 0.05f;   // K*K*S - K*QS
                out[(size_t)(b0 + b) * OUTN + o] = fmaxf(r, 0.0f);
            }
        }

        #pragma unroll
        for (int b = 0; b < 8; ++b) xv[b] = xn[b];
    }
}

extern "C" void kernel_launch(void* const* d_in, const int* in_sizes, int n_in,
                              void* d_out, int out_size, void* d_ws, size_t ws_size,
                              hipStream_t stream) {
    const float* x = (const float*)d_in[0];
    const float* W = (const float*)d_in[1];
    const float* q = (const float*)d_in[2];
    float* out = (float*)d_out;
    _Float16* h = (_Float16*)d_ws;

    cvt_kernel<<<dim3(1280), dim3(256), 0, stream>>>(x, W, q, h);

    const _Float16* xh = h;
    const _Float16* Wh = h + XH_ELEMS;
    const _Float16* qh = h + XH_ELEMS + WH_ELEMS;
    dnm_kernel<<<dim3(512), dim3(256), 0, stream>>>(xh, Wh, qh, out);
}

// Round 10
// 78.757 us; speedup vs baseline: 1.1075x; 1.0697x over previous
//
#include <hip/hip_runtime.h>

// DNM dendritic layer: out[b,o] = max(0, 0.25*S - 0.05),
//   S = sum_{m,i} relu(fma(x[b,i], W[o,m,i], -q[o,m,i]))
// B=512, OUT=128, M=8, IN=512, fp32 in/out.
//
// R10 = R7 (best, 79.2us) with the cvt pre-kernel MERGED into dnm:
// one dispatch, no inter-node drain, no d_ws round-trip. W/q convert
// f32->f16 (RNE) during LDS staging; x converts at register load.
// Compute loop is byte-identical to R7's (fp16 pk_fma/pk_max/dot2,
// absmax 0.5 vs threshold 2.32).
// Lessons kept: no VGPR cap (R2), unroll 2 on m-loop only (R3),
// LDS staging beats streaming (R6/R8), short blocks beat long waves (R9).

#define OUTN 128
#define MM   8
#define INN  512

typedef float    f4 __attribute__((ext_vector_type(4)));
typedef _Float16 h2 __attribute__((ext_vector_type(2)));
typedef _Float16 h4 __attribute__((ext_vector_type(4)));
typedef _Float16 h8 __attribute__((ext_vector_type(8)));

// Block: 256 threads = 4 waves, one o, 32 b's (8/wave).
// Grid: 128 o * 16 b-groups = 2048 blocks. LDS 16 KB.
__global__ __launch_bounds__(256) void dnm_kernel(
    const float* __restrict__ x,   // [B, IN]  fp32
    const float* __restrict__ W,   // [OUT, M, IN]  fp32
    const float* __restrict__ q,   // [OUT, M, IN]  fp32
    float* __restrict__ out)       // [B, OUT]
{
    __shared__ _Float16 lds_w[MM * INN];   // 8 KB
    __shared__ _Float16 lds_q[MM * INN];   // 8 KB

    const int tid  = threadIdx.x;
    const int o    = blockIdx.x >> 4;
    const int bgrp = blockIdx.x & 15;
    const int wave = tid >> 6;
    const int lane = tid & 63;
    const int b0   = bgrp * 32 + wave * 8;
    const int i0   = lane * 8;             // this lane's 8 i's

    // Stage W[o], q[o]: load f32 (coalesced f4), convert RNE, store h4
    // (ds_write_b64). 4096 f32 per array = 4 f4-chunks per thread.
    {
        const f4* Wg = (const f4*)(W + (size_t)o * MM * INN);
        const f4* qg = (const f4*)(q + (size_t)o * MM * INN);
        h4* lw = (h4*)lds_w;
        h4* lq = (h4*)lds_q;
        #pragma unroll
        for (int c = 0; c < 4; ++c) {
            const int j = tid + c * 256;
            lw[j] = __builtin_convertvector(Wg[j], h4);   // RNE
            lq[j] = __builtin_convertvector(qg[j], h4);   // RNE
        }
    }

    // Load + convert this wave's 8 x-rows before the barrier (overlaps
    // other waves' staging). 2 f4 per row -> h8 (32 VGPRs resident).
    h8 xv[8];
    #pragma unroll
    for (int b = 0; b < 8; ++b) {
        const float* xr = x + (size_t)(b0 + b) * INN + i0;
        f4 lo = *(const f4*)xr;
        f4 hi = *(const f4*)(xr + 4);
        h4 l = __builtin_convertvector(lo, h4);
        h4 h = __builtin_convertvector(hi, h4);
        xv[b] = (h8){l[0], l[1], l[2], l[3], h[0], h[1], h[2], h[3]};
    }

    __syncthreads();

    float acc[8];
    #pragma unroll
    for (int b = 0; b < 8; ++b) acc[b] = 0.0f;

    const h2 one = {(_Float16)1.0f, (_Float16)1.0f};

    // R7's proven core: unroll 2 (two m's of fragments live, R3 lesson).
    #pragma unroll 2
    for (int m = 0; m < MM; ++m) {
        const h8 w8 = *(const h8*)(lds_w + m * INN + i0);
        const h8 q8 = *(const h8*)(lds_q + m * INN + i0);
        #pragma unroll
        for (int b = 0; b < 8; ++b) {
            #pragma unroll
            for (int p = 0; p < 4; ++p) {
                // Each h2 is one VGPR of the h8 — no repack.
                h2 xx = {xv[b][2 * p], xv[b][2 * p + 1]};
                h2 ww = {w8[2 * p], w8[2 * p + 1]};
                h2 qq = {q8[2 * p], q8[2 * p + 1]};
                // v_pk_fma_f16 + v_pk_max_f16 + v_dot2_f32_f16
                h2 t = __builtin_elementwise_fma(xx, ww, -qq);
                t = __builtin_elementwise_max(t, (h2)(_Float16)0.0f);
#if __has_builtin(__builtin_amdgcn_fdot2)
                acc[b] = __builtin_amdgcn_fdot2(t, one, acc[b], false);
#else
                acc[b] += (float)t[0] + (float)t[1];
#endif
            }
        }
    }

    // Butterfly-reduce each acc[b] across 64 lanes; lane b writes (b0+b, o).
    #pragma unroll
    for (int b = 0; b < 8; ++b) {
        float v = acc[b];
        v += __shfl_xor(v, 1, 64);
        v += __shfl_xor(v, 2, 64);
        v += __shfl_xor(v, 4, 64);
        v += __shfl_xor(v, 8, 64);
        v += __shfl_xor(v, 16, 64);
        v += __shfl_xor(v, 32, 64);
        if (lane == b) {
            float r = 0.25f * v - 0.05f;   // K*K*S - K*QS
            out[(size_t)(b0 + b) * OUTN + o] = fmaxf(r, 0.0f);
        }
    }
}

extern "C" void kernel_launch(void* const* d_in, const int* in_sizes, int n_in,
                              void* d_out, int out_size, void* d_ws, size_t ws_size,
                              hipStream_t stream) {
    const float* x = (const float*)d_in[0];
    const float* W = (const float*)d_in[1];
    const float* q = (const float*)d_in[2];
    float* out = (float*)d_out;
    dim3 grid(OUTN * 16);   // 128 o * 16 b-groups = 2048 blocks
    dim3 block(256);
    dnm_kernel<<<grid, block, 0, stream>>>(x, W, q, out);
}

// Round 11
// 77.928 us; speedup vs baseline: 1.1193x; 1.0106x over previous
//
#include <hip/hip_runtime.h>

// DNM dendritic layer: out[b,o] = max(0, 0.25*S - 0.05),
//   S = sum_{m,i} relu(fma(x[b,i], W[o,m,i], -q[o,m,i]))
// B=512, OUT=128, M=8, IN=512, fp32 in/out.
//
// R11 = R10 (best, 78.8us) with the b-tile cut 8->4 to minimize VGPR
// (~56) and reach FULL occupancy: 32 waves/CU co-resident (VGPR<=64),
// grid 4096 = 16 blocks/CU in two fully-resident generations. Theory:
// the invariant ~28us kernel wall is load-latency exposure at ~5 waves/CU
// average occupancy (R1 measured 16.6%) on a possibly down-clocked shader
// core; only raw wave count can hide it. Everything else identical to R10:
// merged f32->f16 conversion in staging (RNE), fp16 pk_fma/pk_max/dot2
// core (absmax 0.5 vs thr 2.32), no VGPR cap (R2), unroll 2 m-loop (R3).

#define OUTN 128
#define MM   8
#define INN  512

typedef float    f4 __attribute__((ext_vector_type(4)));
typedef _Float16 h2 __attribute__((ext_vector_type(2)));
typedef _Float16 h4 __attribute__((ext_vector_type(4)));
typedef _Float16 h8 __attribute__((ext_vector_type(8)));

// Block: 256 threads = 4 waves, one o, 16 b's (4/wave).
// Grid: 128 o * 32 b-groups = 4096 blocks. LDS 16 KB.
__global__ __launch_bounds__(256) void dnm_kernel(
    const float* __restrict__ x,   // [B, IN]  fp32
    const float* __restrict__ W,   // [OUT, M, IN]  fp32
    const float* __restrict__ q,   // [OUT, M, IN]  fp32
    float* __restrict__ out)       // [B, OUT]
{
    __shared__ _Float16 lds_w[MM * INN];   // 8 KB
    __shared__ _Float16 lds_q[MM * INN];   // 8 KB

    const int tid  = threadIdx.x;
    const int o    = blockIdx.x >> 5;
    const int bgrp = blockIdx.x & 31;
    const int wave = tid >> 6;
    const int lane = tid & 63;
    const int b0   = bgrp * 16 + wave * 4;
    const int i0   = lane * 8;             // this lane's 8 i's

    // Stage W[o], q[o]: load f32 (coalesced f4), convert RNE, store h4.
    {
        const f4* Wg = (const f4*)(W + (size_t)o * MM * INN);
        const f4* qg = (const f4*)(q + (size_t)o * MM * INN);
        h4* lw = (h4*)lds_w;
        h4* lq = (h4*)lds_q;
        #pragma unroll
        for (int c = 0; c < 4; ++c) {
            const int j = tid + c * 256;
            lw[j] = __builtin_convertvector(Wg[j], h4);   // RNE
            lq[j] = __builtin_convertvector(qg[j], h4);   // RNE
        }
    }

    // Load + convert this wave's 4 x-rows before the barrier (overlaps
    // other waves' staging). 16 VGPRs resident.
    h8 xv[4];
    #pragma unroll
    for (int b = 0; b < 4; ++b) {
        const float* xr = x + (size_t)(b0 + b) * INN + i0;
        f4 lo = *(const f4*)xr;
        f4 hi = *(const f4*)(xr + 4);
        h4 l = __builtin_convertvector(lo, h4);
        h4 h = __builtin_convertvector(hi, h4);
        xv[b] = (h8){l[0], l[1], l[2], l[3], h[0], h[1], h[2], h[3]};
    }

    __syncthreads();

    float acc[4];
    #pragma unroll
    for (int b = 0; b < 4; ++b) acc[b] = 0.0f;

    const h2 one = {(_Float16)1.0f, (_Float16)1.0f};

    // unroll 2: two m's of fragments live (16 regs), not all 8 (R3 lesson).
    #pragma unroll 2
    for (int m = 0; m < MM; ++m) {
        const h8 w8 = *(const h8*)(lds_w + m * INN + i0);
        const h8 q8 = *(const h8*)(lds_q + m * INN + i0);
        #pragma unroll
        for (int b = 0; b < 4; ++b) {
            #pragma unroll
            for (int p = 0; p < 4; ++p) {
                // Each h2 is one VGPR of the h8 — no repack.
                h2 xx = {xv[b][2 * p], xv[b][2 * p + 1]};
                h2 ww = {w8[2 * p], w8[2 * p + 1]};
                h2 qq = {q8[2 * p], q8[2 * p + 1]};
                // v_pk_fma_f16 + v_pk_max_f16 + v_dot2_f32_f16
                h2 t = __builtin_elementwise_fma(xx, ww, -qq);
                t = __builtin_elementwise_max(t, (h2)(_Float16)0.0f);
#if __has_builtin(__builtin_amdgcn_fdot2)
                acc[b] = __builtin_amdgcn_fdot2(t, one, acc[b], false);
#else
                acc[b] += (float)t[0] + (float)t[1];
#endif
            }
        }
    }

    // Butterfly-reduce each acc[b] across 64 lanes; lane b writes (b0+b, o).
    #pragma unroll
    for (int b = 0; b < 4; ++b) {
        float v = acc[b];
        v += __shfl_xor(v, 1, 64);
        v += __shfl_xor(v, 2, 64);
        v += __shfl_xor(v, 4, 64);
        v += __shfl_xor(v, 8, 64);
        v += __shfl_xor(v, 16, 64);
        v += __shfl_xor(v, 32, 64);
        if (lane == b) {
            float r = 0.25f * v - 0.05f;   // K*K*S - K*QS
            out[(size_t)(b0 + b) * OUTN + o] = fmaxf(r, 0.0f);
        }
    }
}

extern "C" void kernel_launch(void* const* d_in, const int* in_sizes, int n_in,
                              void* d_out, int out_size, void* d_ws, size_t ws_size,
                              hipStream_t stream) {
    const float* x = (const float*)d_in[0];
    const float* W = (const float*)d_in[1];
    const float* q = (const float*)d_in[2];
    float* out = (float*)d_out;
    dim3 grid(OUTN * 32);   // 128 o * 32 b-groups = 4096 blocks
    dim3 block(256);
    dnm_kernel<<<grid, block, 0, stream>>>(x, W, q, out);
}